// Round 13
// baseline (195.040 us; speedup 1.0000x reference)
//
#include <hip/hip_runtime.h>

typedef __bf16 bf16;
typedef __bf16 bf16x8 __attribute__((ext_vector_type(8)));
typedef __bf16 bf16x4 __attribute__((ext_vector_type(4)));
typedef float floatx4 __attribute__((ext_vector_type(4)));

#define HIDDEN 1024
#define SEQ 2048
#define BATCH 4
#define ATT_SCALE 0.0625f
#define LN_EPS 1e-5f
#define WW (HIDDEN * HIDDEN)

__device__ __forceinline__ void gload_lds16(const void* g, void* l) {
    __builtin_amdgcn_global_load_lds(
        (const __attribute__((address_space(1))) unsigned int*)g,
        (__attribute__((address_space(3))) unsigned int*)l, 16, 0, 0);
}

#define GBAR() asm volatile("s_barrier" ::: "memory")
#define VMC(N) asm volatile("s_waitcnt vmcnt(" #N ")" ::: "memory")
#define MFMA(a, b, c) __builtin_amdgcn_mfma_f32_16x16x32_bf16(a, b, c, 0, 0, 0)

// ---------------- fp32 -> bf16 conversion ----------------
__global__ void cvt_f32_bf16(const float* __restrict__ in, bf16* __restrict__ out, int n4) {
    int i = blockIdx.x * blockDim.x + threadIdx.x;
    if (i >= n4) return;
    float4 v = ((const float4*)in)[i];
    bf16x4 o;
    o[0] = (bf16)v.x; o[1] = (bf16)v.y; o[2] = (bf16)v.z; o[3] = (bf16)v.w;
    ((bf16x4*)out)[i] = o;
}

// ---------------- transpose 3 weight matrices (fp32 1024x1024 -> bf16 transposed) ----------------
__global__ void transpose_w3(const float* __restrict__ s0, const float* __restrict__ s1,
                             const float* __restrict__ s2,
                             bf16* __restrict__ d0p, bf16* __restrict__ d1p, bf16* __restrict__ d2p) {
    const float* in = (blockIdx.z == 0) ? s0 : (blockIdx.z == 1) ? s1 : s2;
    bf16* out = (blockIdx.z == 0) ? d0p : (blockIdx.z == 1) ? d1p : d2p;
    __shared__ __attribute__((aligned(16))) bf16 tile[64][72];
    const int d0 = blockIdx.x * 64;
    const int f0 = blockIdx.y * 64;
    const int t = threadIdx.x;
    const int r = t >> 4;
    const int c = (t & 15) * 4;
#pragma unroll
    for (int i = 0; i < 4; ++i) {
        float4 v = *(const float4*)&in[(long)(f0 + r + i * 16) * HIDDEN + d0 + c];
        bf16x4 b;
        b[0] = (bf16)v.x; b[1] = (bf16)v.y; b[2] = (bf16)v.z; b[3] = (bf16)v.w;
        *(bf16x4*)&tile[r + i * 16][c] = b;
    }
    __syncthreads();
#pragma unroll
    for (int i = 0; i < 4; ++i) {
        const int dr = r + i * 16;
        bf16x4 o;
#pragma unroll
        for (int j = 0; j < 4; ++j) o[j] = tile[c + j][dr];
        *(bf16x4*)&out[(long)(d0 + dr) * HIDDEN + f0 + c] = o;
    }
}

// ---------------- K32-slot GEMM, 2-slot double buffer (64 KB -> 2 blocks/CU) --------
// C = A (MxK_sub) * B^T, bf16, z = ks*zmod + mat. 512 thr = 8 waves (2M x 4N),
// BM=BN=256, wave tile 128x64. Slot = K-32 chunk: A-unit 16KB + B-unit 16KB.
// Per slot: STAGE slot s+1 into other buffer FIRST (longest runway), then 12
// ds_read_b128, then 32 MFMA (compiler-scheduled counted lgkm interleave),
// then VMC(0) + barrier. The drain is ~free: T_slot >= HBM latency, and the
// co-resident second block covers any residual (the knob this round tests).
// Race proof: buffer (s+1)&1 was last read in slot s-1, completed before that
// slot's end barrier; VMC(0)+barrier at end of s guarantees slot s+1 landed.
// 64B rows with 16B-chunk rotation ((row>>1)+l4)&3 -> measured-zero-conflict
// ds_read_b128; gload_lds dest linear, source inverse-rotated.
// MODE 0: bf16 C = acc*scale ; MODE 4: fp32 C = acc (split-K partial)
template <int MODE>
__global__ __launch_bounds__(512, 2)
void gemmk32(const bf16* A, const bf16* Bw, void* __restrict__ Cout,
             int lda, int ldb, int ldc, int K, float scale,
             long sA, long sB, long sC, int zmod) {
    __shared__ __attribute__((aligned(16))) char lds[65536];

    // XCD-aware block swizzle (per-z nblk % 8 == 0 for all launches)
    const int gx = gridDim.x;
    const int nblk = gx * gridDim.y;
    const int bid = blockIdx.y * gx + blockIdx.x;
    const int cpx = nblk >> 3;
    const int sbid = (nblk & 7) ? bid : (bid & 7) * cpx + (bid >> 3);
    const int bx = sbid % gx, by = sbid / gx;

    const int z = blockIdx.z;
    const int mat = z % zmod, ks = z / zmod;
    const char* Ab = (const char*)(A + (long)mat * sA + (long)ks * K);
    const char* Bb = (const char*)(Bw + (long)mat * sB + (long)ks * K);
    const long lda2 = lda * 2L, ldb2 = ldb * 2L;

    const int t = threadIdx.x;
    const int lane = t & 63;
    const int w = t >> 6;
    const int wm = w >> 2;      // 0..1
    const int wn = w & 3;       // 0..3
    const int l15 = lane & 15;
    const int l4 = lane >> 4;

    const int row0 = by * 256;
    const int col0 = bx * 256;

    // staging sources: gload u covers rows u*128 + t/4, 64B rows; stored chunk
    // (t&3) holds global chunk ((t&3) - ((row>>1)&3)) & 3
    const int sc = ((((t & 3) - ((t >> 3) & 3)) & 3) << 4);
    const char* aS[2];
    const char* bS[2];
#pragma unroll
    for (int uu = 0; uu < 2; ++uu) {
        aS[uu] = Ab + (long)(row0 + uu * 128 + (t >> 2)) * lda2 + sc;
        bS[uu] = Bb + (long)(col0 + uu * 128 + (t >> 2)) * ldb2 + sc;
    }

    auto STAGE = [&](int buf, long koff) {
        char* base = lds + buf * 32768;
        gload_lds16(aS[0] + koff, base + t * 16);
        gload_lds16(aS[1] + koff, base + 8192 + t * 16);
        gload_lds16(bS[0] + koff, base + 16384 + t * 16);
        gload_lds16(bS[1] + koff, base + 24576 + t * 16);
    };

    floatx4 acc[8][4] = {};
    const int ns = K / 32;   // K-32 slots (ns >= 2)

    // prologue: slot 0 -> buf 0
    STAGE(0, 0);
    VMC(0);
    GBAR();

    for (int s = 0; s < ns; ++s) {
        const char* sb = lds + (s & 1) * 32768;

        // stage slot s+1 first (clamped at tail; lands in the never-again-read buffer)
        const long pko = (long)((s + 1 < ns) ? s + 1 : ns - 1) * 64;
        STAGE((s + 1) & 1, pko);

        bf16x8 a[8], b[4];
#pragma unroll
        for (int n = 0; n < 4; ++n) {
            int lr = wn * 64 + n * 16 + l15;
            b[n] = *(const bf16x8*)(sb + 16384 + lr * 64 + ((((lr >> 1) + l4) & 3) << 4));
        }
#pragma unroll
        for (int m = 0; m < 8; ++m) {
            int lr = wm * 128 + m * 16 + l15;
            a[m] = *(const bf16x8*)(sb + lr * 64 + ((((lr >> 1) + l4) & 3) << 4));
        }

        __builtin_amdgcn_s_setprio(1);
#pragma unroll
        for (int m = 0; m < 8; ++m)
#pragma unroll
            for (int n = 0; n < 4; ++n)
                acc[m][n] = MFMA(a[m], b[n], acc[m][n]);
        __builtin_amdgcn_s_setprio(0);

        VMC(0);   // ~free: issued T_slot ago >= HBM latency; 2nd block covers rest
        GBAR();
    }

    // ---- epilogue
    const int rq = l4 * 4;
    if constexpr (MODE == 0) {
        bf16* C = ((bf16*)Cout) + (long)z * sC;
#pragma unroll
        for (int m = 0; m < 8; ++m)
#pragma unroll
            for (int i = 0; i < 4; ++i) {
                long gr = row0 + wm * 128 + m * 16 + rq + i;
#pragma unroll
                for (int n = 0; n < 4; ++n) {
                    int gc = col0 + wn * 64 + n * 16 + l15;
                    C[gr * ldc + gc] = (bf16)(acc[m][n][i] * scale);
                }
            }
    } else {
        float* C = (float*)Cout + (long)z * sC;
#pragma unroll
        for (int m = 0; m < 8; ++m)
#pragma unroll
            for (int i = 0; i < 4; ++i) {
                long gr = row0 + wm * 128 + m * 16 + rq + i;
#pragma unroll
                for (int n = 0; n < 4; ++n) {
                    int gc = col0 + wn * 64 + n * 16 + l15;
                    C[gr * ldc + gc] = acc[m][n][i];
                }
            }
    }
}

// ---------------- reduce Gt/Wc fp32 partials (planes z=ks*2+mat, ks 0..3) -> wgc bf16 ----------------
__global__ void reduce_wgc(const float* __restrict__ p, bf16* __restrict__ out) {
    int i = blockIdx.x * blockDim.x + threadIdx.x;
    int e = i * 4;
    int mat = e >> 20;
    int local = e & (WW - 1);
    float4 s = *(const float4*)(p + (long)mat * WW + local);
#pragma unroll
    for (int ksp = 1; ksp < 4; ++ksp) {
        float4 a = *(const float4*)(p + (long)(ksp * 2 + mat) * WW + local);
        s.x += a.x; s.y += a.y; s.z += a.z; s.w += a.w;
    }
    bf16x4 o;
    o[0] = (bf16)s.x; o[1] = (bf16)s.y; o[2] = (bf16)s.z; o[3] = (bf16)s.w;
    *(bf16x4*)&out[e] = o;
}

// ---------------- row softmax, in-place on bf16 scores ----------------
__global__ void softmax_rows(bf16* __restrict__ S, const int* __restrict__ mask) {
    const int b = blockIdx.y;
    const int row = blockIdx.x;
    bf16* srow = S + ((long)b * SEQ + row) * SEQ;
    const int* mrow = mask + b * SEQ;
    const int t = threadIdx.x;

    bf16x8 sv = *(const bf16x8*)&srow[t * 8];
    int4 m0 = ((const int4*)mrow)[t * 2];
    int4 m1 = ((const int4*)mrow)[t * 2 + 1];
    int mk[8] = {m0.x, m0.y, m0.z, m0.w, m1.x, m1.y, m1.z, m1.w};

    float v[8];
    float mx = -1e30f;
#pragma unroll
    for (int j = 0; j < 8; ++j) {
        float s = (float)sv[j];
        if (mk[j] == 0) s = -1e9f;
        v[j] = s;
        mx = fmaxf(mx, s);
    }
    __shared__ float redm[4], reds[4];
#pragma unroll
    for (int off = 32; off > 0; off >>= 1) mx = fmaxf(mx, __shfl_down(mx, off));
    if ((t & 63) == 0) redm[t >> 6] = mx;
    __syncthreads();
    mx = fmaxf(fmaxf(redm[0], redm[1]), fmaxf(redm[2], redm[3]));

    float sum = 0.f;
#pragma unroll
    for (int j = 0; j < 8; ++j) {
        v[j] = __expf(v[j] - mx);
        sum += v[j];
    }
#pragma unroll
    for (int off = 32; off > 0; off >>= 1) sum += __shfl_down(sum, off);
    if ((t & 63) == 0) reds[t >> 6] = sum;
    __syncthreads();
    sum = reds[0] + reds[1] + reds[2] + reds[3];
    float inv = 1.0f / sum;

    bf16x8 o;
#pragma unroll
    for (int j = 0; j < 8; ++j) o[j] = (bf16)(v[j] * inv);
    *(bf16x8*)&srow[t * 8] = o;
}

// ---------------- transpose VWc (from yv cols 1024..2047): per batch -> (1024 x SEQ) ----------------
__global__ void transpose_v(const bf16* __restrict__ yv, bf16* __restrict__ out) {
    __shared__ __attribute__((aligned(16))) bf16 tile[64][72];
    const int z = blockIdx.z;
    const bf16* ib = yv + (long)z * SEQ * 2048 + 1024;
    bf16* ob = out + (long)z * SEQ * HIDDEN;
    const int d0 = blockIdx.x * 64;
    const int s0 = blockIdx.y * 64;
    const int t = threadIdx.x;
    const int r = t >> 4;
    const int c = (t & 15) * 4;
#pragma unroll
    for (int i = 0; i < 4; ++i) {
        bf16x4 v = *(const bf16x4*)&ib[(long)(s0 + r + i * 16) * 2048 + d0 + c];
        *(bf16x4*)&tile[r + i * 16][c] = v;
    }
    __syncthreads();
#pragma unroll
    for (int i = 0; i < 4; ++i) {
        const int dr = r + i * 16;
        bf16x4 o;
#pragma unroll
        for (int j = 0; j < 4; ++j) o[j] = tile[c + j][dr];
        *(bf16x4*)&ob[(long)(d0 + dr) * SEQ + s0 + c] = o;
    }
}

// ---------------- LayerNorm fused with PV split-K reduce + bias + residual ----------------
__global__ void layernorm_out(const bf16* __restrict__ pp, const float* __restrict__ x,
                              const float* __restrict__ bo, const float* __restrict__ gamma,
                              const float* __restrict__ beta, float* __restrict__ out) {
    const long row = blockIdx.x;
    const int b = (int)(row >> 11);
    const int s = (int)(row & 2047);
    const bf16* r0 = pp + ((long)b * SEQ + s) * HIDDEN;
    const bf16* r1 = r0 + 4L * SEQ * HIDDEN;
    const int t = threadIdx.x;

    bf16x4 a0 = ((const bf16x4*)r0)[t];
    bf16x4 a1 = ((const bf16x4*)r1)[t];
    float4 xv = ((const float4*)(x + row * HIDDEN))[t];
    float4 bv = ((const float4*)bo)[t];
    float4 v;
    v.x = (float)a0[0] + (float)a1[0] + bv.x + xv.x;
    v.y = (float)a0[1] + (float)a1[1] + bv.y + xv.y;
    v.z = (float)a0[2] + (float)a1[2] + bv.z + xv.z;
    v.w = (float)a0[3] + (float)a1[3] + bv.w + xv.w;

    float ssum = v.x + v.y + v.z + v.w;
    float sq = v.x * v.x + v.y * v.y + v.z * v.z + v.w * v.w;
    __shared__ float rs[4], rq[4];
#pragma unroll
    for (int off = 32; off > 0; off >>= 1) {
        ssum += __shfl_down(ssum, off);
        sq += __shfl_down(sq, off);
    }
    if ((t & 63) == 0) { rs[t >> 6] = ssum; rq[t >> 6] = sq; }
    __syncthreads();
    ssum = rs[0] + rs[1] + rs[2] + rs[3];
    sq = rq[0] + rq[1] + rq[2] + rq[3];
    float mu = ssum * (1.0f / HIDDEN);
    float var = sq * (1.0f / HIDDEN) - mu * mu;
    float rinv = rsqrtf(var + LN_EPS);
    float4 g = ((const float4*)gamma)[t];
    float4 bt = ((const float4*)beta)[t];
    float4 o;
    o.x = (v.x - mu) * rinv * g.x + bt.x;
    o.y = (v.y - mu) * rinv * g.y + bt.y;
    o.z = (v.z - mu) * rinv * g.z + bt.z;
    o.w = (v.w - mu) * rinv * g.w + bt.w;
    ((float4*)(out + row * HIDDEN))[t] = o;
}

// ---------------- launch ----------------
extern "C" void kernel_launch(void* const* d_in, const int* in_sizes, int n_in,
                              void* d_out, int out_size, void* d_ws, size_t ws_size,
                              hipStream_t stream) {
    const float* x     = (const float*)d_in[0];
    const int*   mask  = (const int*)d_in[1];
    const float* Wq    = (const float*)d_in[2];
    const float* Wk    = (const float*)d_in[3];
    const float* Wv    = (const float*)d_in[4];
    const float* Wo    = (const float*)d_in[5];
    const float* bo    = (const float*)d_in[6];
    const float* gamma = (const float*)d_in[7];
    const float* beta  = (const float*)d_in[8];
    float* out = (float*)d_out;

    char* ws = (char*)d_ws;
    const long MB = 1024L * 1024L;
    bf16* yv   = (bf16*)(ws + 0 * MB);    // 32 MB (8192 x 2048) [y | VWc]
    bf16* pp   = (bf16*)(ws + 0 * MB);    // 32 MB PV partials (8 planes), after yv dead
    bf16* xb   = (bf16*)(ws + 32 * MB);   // 16 MB
    bf16* vt   = (bf16*)(ws + 48 * MB);   // 16 MB (per batch 1024 x 2048)
    bf16* wgc  = (bf16*)(ws + 64 * MB);   // 4 MB (2048 x 1024): [Gt ; Wc]
    bf16* wkT  = (bf16*)(ws + 68 * MB);   // 2 MB  -- A mat 0
    bf16* wo   = (bf16*)(ws + 70 * MB);   // 2 MB  -- A mat 1
    bf16* wqT  = (bf16*)(ws + 72 * MB);   // 2 MB  -- B mat 0
    bf16* wvT  = (bf16*)(ws + 74 * MB);   // 2 MB  -- B mat 1
    bf16* S    = (bf16*)(ws + 76 * MB);   // 32 MB scores/probs
    float* wgcp = (float*)(ws + 76 * MB); // 32 MB fp32 Gt/Wc partials (before S exists)

    const int BS = BATCH * SEQ;  // 8192
    dim3 blk256(256), blk512(512);

    // input + weight prep
    cvt_f32_bf16<<<dim3(BS * HIDDEN / 4 / 256), blk256, 0, stream>>>(x, xb, BS * HIDDEN / 4);
    cvt_f32_bf16<<<dim3(WW / 4 / 256), blk256, 0, stream>>>(Wo, wo, WW / 4);
    transpose_w3<<<dim3(16, 16, 3), blk256, 0, stream>>>(Wq, Wk, Wv, wqT, wkT, wvT);

    // Gt/Wc split-K=4: z = ks*2 + mat, K_sub=256 (8 slots), fp32 partials. grid (4,4,8)
    gemmk32<4><<<dim3(1024 / 256, 1024 / 256, 8), blk512, 0, stream>>>(
        wkT, wqT, wgcp, HIDDEN, HIDDEN, HIDDEN, 256, 1.0f,
        (long)WW, (long)WW, (long)WW, 2);
    reduce_wgc<<<dim3(2 * WW / 4 / 256), blk256, 0, stream>>>(wgcp, wgc);

    // fused projection: yv = xb * wgc^T (8192 x 2048), K=1024. grid 8x32 = 256
    gemmk32<0><<<dim3(2048 / 256, BS / 256, 1), blk512, 0, stream>>>(
        xb, wgc, yv, HIDDEN, HIDDEN, 2048, HIDDEN, 1.0f, 0, 0, 0, 1);

    // VWc -> vt per batch
    transpose_v<<<dim3(HIDDEN / 64, SEQ / 64, BATCH), blk256, 0, stream>>>(yv, vt);

    // scores: per batch (2048x2048) = y * x^T * SCALE. grid 8x8x4 = 256
    gemmk32<0><<<dim3(SEQ / 256, SEQ / 256, BATCH), blk512, 0, stream>>>(
        yv, xb, S, 2048, HIDDEN, SEQ, HIDDEN, ATT_SCALE,
        (long)SEQ * 2048, (long)SEQ * HIDDEN, (long)SEQ * SEQ, 4);

    softmax_rows<<<dim3(SEQ, BATCH), blk256, 0, stream>>>(S, mask);

    // PV split-K=2: z = ks*4 + b, K_sub=1024 (32 slots), bf16 partials. grid (4,8,8) = 256
    gemmk32<0><<<dim3(HIDDEN / 256, SEQ / 256, 8), blk512, 0, stream>>>(
        S, vt, pp, SEQ, SEQ, HIDDEN, 1024, 1.0f,
        (long)SEQ * SEQ, (long)HIDDEN * SEQ, (long)SEQ * HIDDEN, 4);

    // LN fused with partial-reduce + bias + residual
    layernorm_out<<<dim3(BS), blk256, 0, stream>>>(pp, x, bo, gamma, beta, out);
}

// Round 14
// 186.252 us; speedup vs baseline: 1.0472x; 1.0472x over previous
//
#include <hip/hip_runtime.h>

typedef __bf16 bf16;
typedef __bf16 bf16x8 __attribute__((ext_vector_type(8)));
typedef __bf16 bf16x4 __attribute__((ext_vector_type(4)));
typedef float floatx4 __attribute__((ext_vector_type(4)));

#define HIDDEN 1024
#define SEQ 2048
#define BATCH 4
#define ATT_SCALE 0.0625f
#define LN_EPS 1e-5f
#define WW (HIDDEN * HIDDEN)

__device__ __forceinline__ void gload_lds16(const void* g, void* l) {
    __builtin_amdgcn_global_load_lds(
        (const __attribute__((address_space(1))) unsigned int*)g,
        (__attribute__((address_space(3))) unsigned int*)l, 16, 0, 0);
}

#define GBAR() asm volatile("s_barrier" ::: "memory")
#define LGKM0() asm volatile("s_waitcnt lgkmcnt(0)" ::: "memory")
#define VMC(N) asm volatile("s_waitcnt vmcnt(" #N ")" ::: "memory")
#define MFMA(a, b, c) __builtin_amdgcn_mfma_f32_16x16x32_bf16(a, b, c, 0, 0, 0)

// ---------------- fp32 -> bf16 conversion ----------------
__global__ void cvt_f32_bf16(const float* __restrict__ in, bf16* __restrict__ out, int n4) {
    int i = blockIdx.x * blockDim.x + threadIdx.x;
    if (i >= n4) return;
    float4 v = ((const float4*)in)[i];
    bf16x4 o;
    o[0] = (bf16)v.x; o[1] = (bf16)v.y; o[2] = (bf16)v.z; o[3] = (bf16)v.w;
    ((bf16x4*)out)[i] = o;
}

// ---------------- transpose 3 weight matrices (fp32 1024x1024 -> bf16 transposed) ----------------
__global__ void transpose_w3(const float* __restrict__ s0, const float* __restrict__ s1,
                             const float* __restrict__ s2,
                             bf16* __restrict__ d0p, bf16* __restrict__ d1p, bf16* __restrict__ d2p) {
    const float* in = (blockIdx.z == 0) ? s0 : (blockIdx.z == 1) ? s1 : s2;
    bf16* out = (blockIdx.z == 0) ? d0p : (blockIdx.z == 1) ? d1p : d2p;
    __shared__ __attribute__((aligned(16))) bf16 tile[64][72];
    const int d0 = blockIdx.x * 64;
    const int f0 = blockIdx.y * 64;
    const int t = threadIdx.x;
    const int r = t >> 4;
    const int c = (t & 15) * 4;
#pragma unroll
    for (int i = 0; i < 4; ++i) {
        float4 v = *(const float4*)&in[(long)(f0 + r + i * 16) * HIDDEN + d0 + c];
        bf16x4 b;
        b[0] = (bf16)v.x; b[1] = (bf16)v.y; b[2] = (bf16)v.z; b[3] = (bf16)v.w;
        *(bf16x4*)&tile[r + i * 16][c] = b;
    }
    __syncthreads();
#pragma unroll
    for (int i = 0; i < 4; ++i) {
        const int dr = r + i * 16;
        bf16x4 o;
#pragma unroll
        for (int j = 0; j < 4; ++j) o[j] = tile[c + j][dr];
        *(bf16x4*)&out[(long)(d0 + dr) * HIDDEN + f0 + c] = o;
    }
}

// ---------------- 8-phase GEMM (m201-faithful): C = A (MxK_sub) * B^T, z = ks*zmod + mat
// 512 thr = 8 waves (2M x 4N), BM=BN=256, wave tile 128x64, BK=64.
// LDS 128KB: 2 bufs x 4 units {A-k0, B-k0, A-k1, B-k1}, each 16KB = 256 rows x 64B,
// 16B-chunk rotation (measured-zero-conflict ds_read_b128); gload_lds dest linear,
// source inverse-rotated. 4 phases per K-tile, 16 MFMA each; ONE 2-gload unit
// staged per phase; per phase: reads -> raw s_barrier (issue-only, no drain) ->
// per-wave lgkmcnt(0) [NO sched_barrier: that was m141's -40% poison] -> setprio
// MFMA -> barrier. The leading barrier + per-wave lgkm0 creates bounded wave
// skew: fast waves' MFMA overlaps slow waves' LDS reads. Counted vmcnt(4) only
// at ends of ph1/ph3 (completes units staged 3-4 phases earlier); never drains.
// MODE 0: bf16 C=acc*scale ; MODE 4: fp32 C=acc (split-K partial).
template <int MODE>
__global__ __launch_bounds__(512, 2)
void gemm8p(const bf16* A, const bf16* Bw, void* __restrict__ Cout,
            int lda, int ldb, int ldc, int K, float scale,
            long sA, long sB, long sC, int zmod) {
    __shared__ __attribute__((aligned(16))) char lds[131072];

    // XCD-aware block swizzle (per-z nblk % 8 == 0 for all launches)
    const int gx = gridDim.x;
    const int nblk = gx * gridDim.y;
    const int bid = blockIdx.y * gx + blockIdx.x;
    const int cpx = nblk >> 3;
    const int sbid = (nblk & 7) ? bid : (bid & 7) * cpx + (bid >> 3);
    const int bx = sbid % gx, by = sbid / gx;

    const int z = blockIdx.z;
    const int mat = z % zmod, ks = z / zmod;
    const char* Ab = (const char*)(A + (long)mat * sA + (long)ks * K);
    const char* Bb = (const char*)(Bw + (long)mat * sB + (long)ks * K);
    const long lda2 = lda * 2L, ldb2 = ldb * 2L;

    const int t = threadIdx.x;
    const int lane = t & 63;
    const int w = t >> 6;
    const int wm = w >> 2;      // 0..1
    const int wn = w & 3;       // 0..3
    const int l15 = lane & 15;
    const int l4 = lane >> 4;

    const int row0 = by * 256;
    const int col0 = bx * 256;

    // staging sources: unit covers 256 rows x 64B; thread t, sub uu: row = uu*128 + t/4,
    // stored chunk (t&3) holds global chunk ((t&3) - ((row>>1)&3)) & 3
    const int sc = ((((t & 3) - ((t >> 3) & 3)) & 3) << 4);
    const char* aS[2];
    const char* bS[2];
#pragma unroll
    for (int uu = 0; uu < 2; ++uu) {
        aS[uu] = Ab + (long)(row0 + uu * 128 + (t >> 2)) * lda2 + sc;
        bS[uu] = Bb + (long)(col0 + uu * 128 + (t >> 2)) * ldb2 + sc;
    }

    auto STAGE = [&](char* dstu, const char* const* sp, long koff) {
        gload_lds16(sp[0] + koff, dstu + t * 16);
        gload_lds16(sp[1] + koff, dstu + 8192 + t * 16);
    };

    floatx4 acc[8][4] = {};
    const int nk = K / 64;

    // prologue: tile0's 4 units in consumption order
    STAGE(lds + 0,     aS, 0);      // A-k0
    STAGE(lds + 16384, bS, 0);      // B-k0
    STAGE(lds + 32768, aS, 64);     // A-k1
    STAGE(lds + 49152, bS, 64);     // B-k1
    VMC(4);                          // A-k0, B-k0 landed
    GBAR();

    for (int tt = 0; tt < nk; ++tt) {
        const char* cb = lds + (tt & 1) * 65536;
        char* nb = lds + ((tt & 1) ^ 1) * 65536;
        const long nko = (long)((tt + 1 < nk) ? tt + 1 : nk - 1) * 128;

        auto RDA = [&](int kk, int m) {
            int lr = wm * 128 + m * 16 + l15;
            return *(const bf16x8*)(cb + kk * 32768 + lr * 64 + ((((lr >> 1) + l4) & 3) << 4));
        };
        auto RDB = [&](int kk, int n) {
            int lr = wn * 64 + n * 16 + l15;
            return *(const bf16x8*)(cb + 16384 + kk * 32768 + lr * 64 + ((((lr >> 1) + l4) & 3) << 4));
        };

        bf16x8 a[4], b0[4], b1[4];

        // ---- phase 0: A-k0 m0-3 + B-k0; stage A-k0(t+1)
#pragma unroll
        for (int m = 0; m < 4; ++m) a[m] = RDA(0, m);
#pragma unroll
        for (int n = 0; n < 4; ++n) b0[n] = RDB(0, n);
        STAGE(nb + 0, aS, nko);
        GBAR();
        LGKM0();
        __builtin_amdgcn_s_setprio(1);
#pragma unroll
        for (int m = 0; m < 4; ++m)
#pragma unroll
            for (int n = 0; n < 4; ++n) acc[m][n] = MFMA(a[m], b0[n], acc[m][n]);
        __builtin_amdgcn_s_setprio(0);
        GBAR();

        // ---- phase 1: A-k0 m4-7; stage B-k0(t+1); wait: A-k1,B-k1(t) landed
#pragma unroll
        for (int m = 0; m < 4; ++m) a[m] = RDA(0, 4 + m);
        STAGE(nb + 16384, bS, nko);
        GBAR();
        LGKM0();
        __builtin_amdgcn_s_setprio(1);
#pragma unroll
        for (int m = 0; m < 4; ++m)
#pragma unroll
            for (int n = 0; n < 4; ++n) acc[4 + m][n] = MFMA(a[m], b0[n], acc[4 + m][n]);
        __builtin_amdgcn_s_setprio(0);
        VMC(4);
        GBAR();

        // ---- phase 2: A-k1 m0-3 + B-k1; stage A-k1(t+1)
#pragma unroll
        for (int m = 0; m < 4; ++m) a[m] = RDA(1, m);
#pragma unroll
        for (int n = 0; n < 4; ++n) b1[n] = RDB(1, n);
        STAGE(nb + 32768, aS, nko + 64);
        GBAR();
        LGKM0();
        __builtin_amdgcn_s_setprio(1);
#pragma unroll
        for (int m = 0; m < 4; ++m)
#pragma unroll
            for (int n = 0; n < 4; ++n) acc[m][n] = MFMA(a[m], b1[n], acc[m][n]);
        __builtin_amdgcn_s_setprio(0);
        GBAR();

        // ---- phase 3: A-k1 m4-7; stage B-k1(t+1); wait: A-k0,B-k0(t+1) landed
#pragma unroll
        for (int m = 0; m < 4; ++m) a[m] = RDA(1, 4 + m);
        STAGE(nb + 49152, bS, nko + 64);
        GBAR();
        LGKM0();
        __builtin_amdgcn_s_setprio(1);
#pragma unroll
        for (int m = 0; m < 4; ++m)
#pragma unroll
            for (int n = 0; n < 4; ++n) acc[4 + m][n] = MFMA(a[m], b1[n], acc[4 + m][n]);
        __builtin_amdgcn_s_setprio(0);
        VMC(4);
        GBAR();
    }
    VMC(0);

    // ---- epilogue
    const int rq = l4 * 4;
    if constexpr (MODE == 0) {
        bf16* C = ((bf16*)Cout) + (long)z * sC;
#pragma unroll
        for (int m = 0; m < 8; ++m)
#pragma unroll
            for (int i = 0; i < 4; ++i) {
                long gr = row0 + wm * 128 + m * 16 + rq + i;
#pragma unroll
                for (int n = 0; n < 4; ++n) {
                    int gc = col0 + wn * 64 + n * 16 + l15;
                    C[gr * ldc + gc] = (bf16)(acc[m][n][i] * scale);
                }
            }
    } else {
        float* C = (float*)Cout + (long)z * sC;
#pragma unroll
        for (int m = 0; m < 8; ++m)
#pragma unroll
            for (int i = 0; i < 4; ++i) {
                long gr = row0 + wm * 128 + m * 16 + rq + i;
#pragma unroll
                for (int n = 0; n < 4; ++n) {
                    int gc = col0 + wn * 64 + n * 16 + l15;
                    C[gr * ldc + gc] = acc[m][n][i];
                }
            }
    }
}

// ---------------- reduce Gt/Wc fp32 partials (planes z=ks*2+mat, ks 0..3) -> wgc bf16 ----------------
__global__ void reduce_wgc(const float* __restrict__ p, bf16* __restrict__ out) {
    int i = blockIdx.x * blockDim.x + threadIdx.x;
    int e = i * 4;
    int mat = e >> 20;
    int local = e & (WW - 1);
    float4 s = *(const float4*)(p + (long)mat * WW + local);
#pragma unroll
    for (int ksp = 1; ksp < 4; ++ksp) {
        float4 a = *(const float4*)(p + (long)(ksp * 2 + mat) * WW + local);
        s.x += a.x; s.y += a.y; s.z += a.z; s.w += a.w;
    }
    bf16x4 o;
    o[0] = (bf16)s.x; o[1] = (bf16)s.y; o[2] = (bf16)s.z; o[3] = (bf16)s.w;
    *(bf16x4*)&out[e] = o;
}

// ---------------- row softmax, in-place on bf16 scores ----------------
__global__ void softmax_rows(bf16* __restrict__ S, const int* __restrict__ mask) {
    const int b = blockIdx.y;
    const int row = blockIdx.x;
    bf16* srow = S + ((long)b * SEQ + row) * SEQ;
    const int* mrow = mask + b * SEQ;
    const int t = threadIdx.x;

    bf16x8 sv = *(const bf16x8*)&srow[t * 8];
    int4 m0 = ((const int4*)mrow)[t * 2];
    int4 m1 = ((const int4*)mrow)[t * 2 + 1];
    int mk[8] = {m0.x, m0.y, m0.z, m0.w, m1.x, m1.y, m1.z, m1.w};

    float v[8];
    float mx = -1e30f;
#pragma unroll
    for (int j = 0; j < 8; ++j) {
        float s = (float)sv[j];
        if (mk[j] == 0) s = -1e9f;
        v[j] = s;
        mx = fmaxf(mx, s);
    }
    __shared__ float redm[4], reds[4];
#pragma unroll
    for (int off = 32; off > 0; off >>= 1) mx = fmaxf(mx, __shfl_down(mx, off));
    if ((t & 63) == 0) redm[t >> 6] = mx;
    __syncthreads();
    mx = fmaxf(fmaxf(redm[0], redm[1]), fmaxf(redm[2], redm[3]));

    float sum = 0.f;
#pragma unroll
    for (int j = 0; j < 8; ++j) {
        v[j] = __expf(v[j] - mx);
        sum += v[j];
    }
#pragma unroll
    for (int off = 32; off > 0; off >>= 1) sum += __shfl_down(sum, off);
    if ((t & 63) == 0) reds[t >> 6] = sum;
    __syncthreads();
    sum = reds[0] + reds[1] + reds[2] + reds[3];
    float inv = 1.0f / sum;

    bf16x8 o;
#pragma unroll
    for (int j = 0; j < 8; ++j) o[j] = (bf16)(v[j] * inv);
    *(bf16x8*)&srow[t * 8] = o;
}

// ---------------- transpose VWc (from yv cols 1024..2047): per batch -> (1024 x SEQ) ----------------
__global__ void transpose_v(const bf16* __restrict__ yv, bf16* __restrict__ out) {
    __shared__ __attribute__((aligned(16))) bf16 tile[64][72];
    const int z = blockIdx.z;
    const bf16* ib = yv + (long)z * SEQ * 2048 + 1024;
    bf16* ob = out + (long)z * SEQ * HIDDEN;
    const int d0 = blockIdx.x * 64;
    const int s0 = blockIdx.y * 64;
    const int t = threadIdx.x;
    const int r = t >> 4;
    const int c = (t & 15) * 4;
#pragma unroll
    for (int i = 0; i < 4; ++i) {
        bf16x4 v = *(const bf16x4*)&ib[(long)(s0 + r + i * 16) * 2048 + d0 + c];
        *(bf16x4*)&tile[r + i * 16][c] = v;
    }
    __syncthreads();
#pragma unroll
    for (int i = 0; i < 4; ++i) {
        const int dr = r + i * 16;
        bf16x4 o;
#pragma unroll
        for (int j = 0; j < 4; ++j) o[j] = tile[c + j][dr];
        *(bf16x4*)&ob[(long)(d0 + dr) * SEQ + s0 + c] = o;
    }
}

// ---------------- LayerNorm fused with PV split-K reduce + bias + residual ----------------
__global__ void layernorm_out(const bf16* __restrict__ pp, const float* __restrict__ x,
                              const float* __restrict__ bo, const float* __restrict__ gamma,
                              const float* __restrict__ beta, float* __restrict__ out) {
    const long row = blockIdx.x;
    const int b = (int)(row >> 11);
    const int s = (int)(row & 2047);
    const bf16* r0 = pp + ((long)b * SEQ + s) * HIDDEN;
    const bf16* r1 = r0 + 4L * SEQ * HIDDEN;
    const int t = threadIdx.x;

    bf16x4 a0 = ((const bf16x4*)r0)[t];
    bf16x4 a1 = ((const bf16x4*)r1)[t];
    float4 xv = ((const float4*)(x + row * HIDDEN))[t];
    float4 bv = ((const float4*)bo)[t];
    float4 v;
    v.x = (float)a0[0] + (float)a1[0] + bv.x + xv.x;
    v.y = (float)a0[1] + (float)a1[1] + bv.y + xv.y;
    v.z = (float)a0[2] + (float)a1[2] + bv.z + xv.z;
    v.w = (float)a0[3] + (float)a1[3] + bv.w + xv.w;

    float ssum = v.x + v.y + v.z + v.w;
    float sq = v.x * v.x + v.y * v.y + v.z * v.z + v.w * v.w;
    __shared__ float rs[4], rq[4];
#pragma unroll
    for (int off = 32; off > 0; off >>= 1) {
        ssum += __shfl_down(ssum, off);
        sq += __shfl_down(sq, off);
    }
    if ((t & 63) == 0) { rs[t >> 6] = ssum; rq[t >> 6] = sq; }
    __syncthreads();
    ssum = rs[0] + rs[1] + rs[2] + rs[3];
    sq = rq[0] + rq[1] + rq[2] + rq[3];
    float mu = ssum * (1.0f / HIDDEN);
    float var = sq * (1.0f / HIDDEN) - mu * mu;
    float rinv = rsqrtf(var + LN_EPS);
    float4 g = ((const float4*)gamma)[t];
    float4 bt = ((const float4*)beta)[t];
    float4 o;
    o.x = (v.x - mu) * rinv * g.x + bt.x;
    o.y = (v.y - mu) * rinv * g.y + bt.y;
    o.z = (v.z - mu) * rinv * g.z + bt.z;
    o.w = (v.w - mu) * rinv * g.w + bt.w;
    ((float4*)(out + row * HIDDEN))[t] = o;
}

// ---------------- launch ----------------
extern "C" void kernel_launch(void* const* d_in, const int* in_sizes, int n_in,
                              void* d_out, int out_size, void* d_ws, size_t ws_size,
                              hipStream_t stream) {
    const float* x     = (const float*)d_in[0];
    const int*   mask  = (const int*)d_in[1];
    const float* Wq    = (const float*)d_in[2];
    const float* Wk    = (const float*)d_in[3];
    const float* Wv    = (const float*)d_in[4];
    const float* Wo    = (const float*)d_in[5];
    const float* bo    = (const float*)d_in[6];
    const float* gamma = (const float*)d_in[7];
    const float* beta  = (const float*)d_in[8];
    float* out = (float*)d_out;

    char* ws = (char*)d_ws;
    const long MB = 1024L * 1024L;
    bf16* yv   = (bf16*)(ws + 0 * MB);    // 32 MB (8192 x 2048) [y | VWc]
    bf16* pp   = (bf16*)(ws + 0 * MB);    // 32 MB PV partials (8 planes), after yv dead
    bf16* xb   = (bf16*)(ws + 32 * MB);   // 16 MB
    bf16* vt   = (bf16*)(ws + 48 * MB);   // 16 MB (per batch 1024 x 2048)
    bf16* wgc  = (bf16*)(ws + 64 * MB);   // 4 MB (2048 x 1024): [Gt ; Wc]
    bf16* wkT  = (bf16*)(ws + 68 * MB);   // 2 MB  -- A mat 0
    bf16* wo   = (bf16*)(ws + 70 * MB);   // 2 MB  -- A mat 1
    bf16* wqT  = (bf16*)(ws + 72 * MB);   // 2 MB  -- B mat 0
    bf16* wvT  = (bf16*)(ws + 74 * MB);   // 2 MB  -- B mat 1
    bf16* S    = (bf16*)(ws + 76 * MB);   // 32 MB scores/probs
    float* wgcp = (float*)(ws + 76 * MB); // 32 MB fp32 Gt/Wc partials (before S exists)

    const int BS = BATCH * SEQ;  // 8192
    dim3 blk256(256), blk512(512);

    // input + weight prep
    cvt_f32_bf16<<<dim3(BS * HIDDEN / 4 / 256), blk256, 0, stream>>>(x, xb, BS * HIDDEN / 4);
    cvt_f32_bf16<<<dim3(WW / 4 / 256), blk256, 0, stream>>>(Wo, wo, WW / 4);
    transpose_w3<<<dim3(16, 16, 3), blk256, 0, stream>>>(Wq, Wk, Wv, wqT, wkT, wvT);

    // Gt/Wc split-K=4: z = ks*2 + mat, K_sub=256 (4 tiles), fp32 partials. grid (4,4,8)
    gemm8p<4><<<dim3(1024 / 256, 1024 / 256, 8), blk512, 0, stream>>>(
        wkT, wqT, wgcp, HIDDEN, HIDDEN, HIDDEN, 256, 1.0f,
        (long)WW, (long)WW, (long)WW, 2);
    reduce_wgc<<<dim3(2 * WW / 4 / 256), blk256, 0, stream>>>(wgcp, wgc);

    // fused projection: yv = xb * wgc^T (8192 x 2048), K=1024. grid 8x32 = 256
    gemm8p<0><<<dim3(2048 / 256, BS / 256, 1), blk512, 0, stream>>>(
        xb, wgc, yv, HIDDEN, HIDDEN, 2048, HIDDEN, 1.0f, 0, 0, 0, 1);

    // VWc -> vt per batch
    transpose_v<<<dim3(HIDDEN / 64, SEQ / 64, BATCH), blk256, 0, stream>>>(yv, vt);

    // scores: per batch (2048x2048) = y * x^T * SCALE. grid 8x8x4 = 256
    gemm8p<0><<<dim3(SEQ / 256, SEQ / 256, BATCH), blk512, 0, stream>>>(
        yv, xb, S, 2048, HIDDEN, SEQ, HIDDEN, ATT_SCALE,
        (long)SEQ * 2048, (long)SEQ * HIDDEN, (long)SEQ * SEQ, 4);

    softmax_rows<<<dim3(SEQ, BATCH), blk256, 0, stream>>>(S, mask);

    // PV split-K=2: z = ks*4 + b, K_sub=1024 (16 tiles), bf16 partials. grid (4,8,8) = 256
    gemm8p<0><<<dim3(HIDDEN / 256, SEQ / 256, 8), blk512, 0, stream>>>(
        S, vt, pp, SEQ, SEQ, HIDDEN, 1024, 1.0f,
        (long)SEQ * SEQ, (long)HIDDEN * SEQ, (long)SEQ * HIDDEN, 4);

    // LN fused with partial-reduce + bias + residual
    layernorm_out<<<dim3(BS), blk256, 0, stream>>>(pp, x, bo, gamma, beta, out);
}

// Round 15
// 169.699 us; speedup vs baseline: 1.1493x; 1.0975x over previous
//
#include <hip/hip_runtime.h>

typedef __bf16 bf16;
typedef __bf16 bf16x8 __attribute__((ext_vector_type(8)));
typedef __bf16 bf16x4 __attribute__((ext_vector_type(4)));
typedef float floatx4 __attribute__((ext_vector_type(4)));

#define HIDDEN 1024
#define SEQ 2048
#define BATCH 4
#define ATT_SCALE 0.0625f
#define LN_EPS 1e-5f
#define WW (HIDDEN * HIDDEN)

__device__ __forceinline__ void gload_lds16(const void* g, void* l) {
    __builtin_amdgcn_global_load_lds(
        (const __attribute__((address_space(1))) unsigned int*)g,
        (__attribute__((address_space(3))) unsigned int*)l, 16, 0, 0);
}

#define GBAR() asm volatile("s_barrier" ::: "memory")
#define LGKM0() asm volatile("s_waitcnt lgkmcnt(0)" ::: "memory")
#define VMC(N) asm volatile("s_waitcnt vmcnt(" #N ")" ::: "memory")
#define MFMA(a, b, c) __builtin_amdgcn_mfma_f32_16x16x32_bf16(a, b, c, 0, 0, 0)
#define MFMA8(a, b, c) __builtin_amdgcn_mfma_f32_16x16x32_fp8_fp8(a, b, c, 0, 0, 0)

// fp8 e4m3 conversions via hardware cvt_pk (saturating)
__device__ __forceinline__ unsigned char to_fp8(float f) {
    return (unsigned char)(__builtin_amdgcn_cvt_pk_fp8_f32(f, 0.0f, 0, 0) & 0xff);
}
__device__ __forceinline__ unsigned int to_fp8x2(float a, float b) {
    return __builtin_amdgcn_cvt_pk_fp8_f32(a, b, 0, 0) & 0xffff;
}

// ---------------- fp32 -> bf16 conversion ----------------
__global__ void cvt_f32_bf16(const float* __restrict__ in, bf16* __restrict__ out, int n4) {
    int i = blockIdx.x * blockDim.x + threadIdx.x;
    if (i >= n4) return;
    float4 v = ((const float4*)in)[i];
    bf16x4 o;
    o[0] = (bf16)v.x; o[1] = (bf16)v.y; o[2] = (bf16)v.z; o[3] = (bf16)v.w;
    ((bf16x4*)out)[i] = o;
}

// ---------------- fp32 -> fp8 conversion (8 elems/thread) ----------------
__global__ void cvt_f32_fp8(const float* __restrict__ in, unsigned char* __restrict__ out, int n8) {
    int i = blockIdx.x * blockDim.x + threadIdx.x;
    if (i >= n8) return;
    float4 v0 = ((const float4*)in)[i * 2];
    float4 v1 = ((const float4*)in)[i * 2 + 1];
    unsigned int lo = to_fp8x2(v0.x, v0.y) | (to_fp8x2(v0.z, v0.w) << 16);
    unsigned int hi = to_fp8x2(v1.x, v1.y) | (to_fp8x2(v1.z, v1.w) << 16);
    ((uint2*)out)[i] = make_uint2(lo, hi);
}

// ---------------- transpose 3 weight matrices (fp32 -> bf16 transposed) ----------------
__global__ void transpose_w3(const float* __restrict__ s0, const float* __restrict__ s1,
                             const float* __restrict__ s2,
                             bf16* __restrict__ d0p, bf16* __restrict__ d1p, bf16* __restrict__ d2p) {
    const float* in = (blockIdx.z == 0) ? s0 : (blockIdx.z == 1) ? s1 : s2;
    bf16* out = (blockIdx.z == 0) ? d0p : (blockIdx.z == 1) ? d1p : d2p;
    __shared__ __attribute__((aligned(16))) bf16 tile[64][72];
    const int d0 = blockIdx.x * 64;
    const int f0 = blockIdx.y * 64;
    const int t = threadIdx.x;
    const int r = t >> 4;
    const int c = (t & 15) * 4;
#pragma unroll
    for (int i = 0; i < 4; ++i) {
        float4 v = *(const float4*)&in[(long)(f0 + r + i * 16) * HIDDEN + d0 + c];
        bf16x4 b;
        b[0] = (bf16)v.x; b[1] = (bf16)v.y; b[2] = (bf16)v.z; b[3] = (bf16)v.w;
        *(bf16x4*)&tile[r + i * 16][c] = b;
    }
    __syncthreads();
#pragma unroll
    for (int i = 0; i < 4; ++i) {
        const int dr = r + i * 16;
        bf16x4 o;
#pragma unroll
        for (int j = 0; j < 4; ++j) o[j] = tile[c + j][dr];
        *(bf16x4*)&out[(long)(d0 + dr) * HIDDEN + f0 + c] = o;
    }
}

// ---------------- bf16 8-phase GEMM (weight prep only): C = A*B^T, z = ks*zmod + mat
template <int MODE>
__global__ __launch_bounds__(512, 2)
void gemm8p(const bf16* A, const bf16* Bw, void* __restrict__ Cout,
            int lda, int ldb, int ldc, int K, float scale,
            long sA, long sB, long sC, int zmod) {
    __shared__ __attribute__((aligned(16))) char lds[131072];

    const int gx = gridDim.x;
    const int nblk = gx * gridDim.y;
    const int bid = blockIdx.y * gx + blockIdx.x;
    const int cpx = nblk >> 3;
    const int sbid = (nblk & 7) ? bid : (bid & 7) * cpx + (bid >> 3);
    const int bx = sbid % gx, by = sbid / gx;

    const int z = blockIdx.z;
    const int mat = z % zmod, ks = z / zmod;
    const char* Ab = (const char*)(A + (long)mat * sA + (long)ks * K);
    const char* Bb = (const char*)(Bw + (long)mat * sB + (long)ks * K);
    const long lda2 = lda * 2L, ldb2 = ldb * 2L;

    const int t = threadIdx.x;
    const int lane = t & 63;
    const int w = t >> 6;
    const int wm = w >> 2;
    const int wn = w & 3;
    const int l15 = lane & 15;
    const int l4 = lane >> 4;

    const int row0 = by * 256;
    const int col0 = bx * 256;

    const int sc = ((((t & 3) - ((t >> 3) & 3)) & 3) << 4);
    const char* aS[2];
    const char* bS[2];
#pragma unroll
    for (int uu = 0; uu < 2; ++uu) {
        aS[uu] = Ab + (long)(row0 + uu * 128 + (t >> 2)) * lda2 + sc;
        bS[uu] = Bb + (long)(col0 + uu * 128 + (t >> 2)) * ldb2 + sc;
    }

    auto STAGE = [&](char* dstu, const char* const* sp, long koff) {
        gload_lds16(sp[0] + koff, dstu + t * 16);
        gload_lds16(sp[1] + koff, dstu + 8192 + t * 16);
    };

    floatx4 acc[8][4] = {};
    const int nk = K / 64;

    STAGE(lds + 0,     aS, 0);
    STAGE(lds + 16384, bS, 0);
    STAGE(lds + 32768, aS, 64);
    STAGE(lds + 49152, bS, 64);
    VMC(4);
    GBAR();

    for (int tt = 0; tt < nk; ++tt) {
        const char* cb = lds + (tt & 1) * 65536;
        char* nb = lds + ((tt & 1) ^ 1) * 65536;
        const long nko = (long)((tt + 1 < nk) ? tt + 1 : nk - 1) * 128;

        auto RDA = [&](int kk, int m) {
            int lr = wm * 128 + m * 16 + l15;
            return *(const bf16x8*)(cb + kk * 32768 + lr * 64 + ((((lr >> 1) + l4) & 3) << 4));
        };
        auto RDB = [&](int kk, int n) {
            int lr = wn * 64 + n * 16 + l15;
            return *(const bf16x8*)(cb + 16384 + kk * 32768 + lr * 64 + ((((lr >> 1) + l4) & 3) << 4));
        };

        bf16x8 a[4], b0[4], b1[4];

#pragma unroll
        for (int m = 0; m < 4; ++m) a[m] = RDA(0, m);
#pragma unroll
        for (int n = 0; n < 4; ++n) b0[n] = RDB(0, n);
        STAGE(nb + 0, aS, nko);
        GBAR();
        LGKM0();
        __builtin_amdgcn_s_setprio(1);
#pragma unroll
        for (int m = 0; m < 4; ++m)
#pragma unroll
            for (int n = 0; n < 4; ++n) acc[m][n] = MFMA(a[m], b0[n], acc[m][n]);
        __builtin_amdgcn_s_setprio(0);
        GBAR();

#pragma unroll
        for (int m = 0; m < 4; ++m) a[m] = RDA(0, 4 + m);
        STAGE(nb + 16384, bS, nko);
        GBAR();
        LGKM0();
        __builtin_amdgcn_s_setprio(1);
#pragma unroll
        for (int m = 0; m < 4; ++m)
#pragma unroll
            for (int n = 0; n < 4; ++n) acc[4 + m][n] = MFMA(a[m], b0[n], acc[4 + m][n]);
        __builtin_amdgcn_s_setprio(0);
        VMC(4);
        GBAR();

#pragma unroll
        for (int m = 0; m < 4; ++m) a[m] = RDA(1, m);
#pragma unroll
        for (int n = 0; n < 4; ++n) b1[n] = RDB(1, n);
        STAGE(nb + 32768, aS, nko + 64);
        GBAR();
        LGKM0();
        __builtin_amdgcn_s_setprio(1);
#pragma unroll
        for (int m = 0; m < 4; ++m)
#pragma unroll
            for (int n = 0; n < 4; ++n) acc[m][n] = MFMA(a[m], b1[n], acc[m][n]);
        __builtin_amdgcn_s_setprio(0);
        GBAR();

#pragma unroll
        for (int m = 0; m < 4; ++m) a[m] = RDA(1, 4 + m);
        STAGE(nb + 49152, bS, nko + 64);
        GBAR();
        LGKM0();
        __builtin_amdgcn_s_setprio(1);
#pragma unroll
        for (int m = 0; m < 4; ++m)
#pragma unroll
            for (int n = 0; n < 4; ++n) acc[4 + m][n] = MFMA(a[m], b1[n], acc[4 + m][n]);
        __builtin_amdgcn_s_setprio(0);
        VMC(4);
        GBAR();
    }
    VMC(0);

    const int rq = l4 * 4;
    if constexpr (MODE == 0) {
        bf16* C = ((bf16*)Cout) + (long)z * sC;
#pragma unroll
        for (int m = 0; m < 8; ++m)
#pragma unroll
            for (int i = 0; i < 4; ++i) {
                long gr = row0 + wm * 128 + m * 16 + rq + i;
#pragma unroll
                for (int n = 0; n < 4; ++n) {
                    int gc = col0 + wn * 64 + n * 16 + l15;
                    C[gr * ldc + gc] = (bf16)(acc[m][n][i] * scale);
                }
            }
    } else {
        float* C = (float*)Cout + (long)z * sC;
#pragma unroll
        for (int m = 0; m < 8; ++m)
#pragma unroll
            for (int i = 0; i < 4; ++i) {
                long gr = row0 + wm * 128 + m * 16 + rq + i;
#pragma unroll
                for (int n = 0; n < 4; ++n) {
                    int gc = col0 + wn * 64 + n * 16 + l15;
                    C[gr * ldc + gc] = acc[m][n][i];
                }
            }
    }
}

// ---------------- fp8 GEMM: C = A (MxK_sub) * B^T, fp8 e4m3 inputs, z = ks*zmod + mat
// 512 thr = 8 waves (2M x 4N), BM=BN=256, wave tile 128x64, K-64 slots.
// LDS 64KB: 2 slots x {A-k0 8K, A-k1 8K, B-k0 8K, B-k1 8K}; unit = 256 rows x 32B.
// 16B-half rotation u' = (u + (r>>2)) & 1 -> <=2-way bank aliasing (free) on
// ds_read_b64 fragments; gload_lds dest linear, source inverse-rotated.
// Per slot: STAGE slot s+1 first (full-slot runway >= HBM latency), 24 b64
// fragment reads + 64 MFMA (compiler-interleaved), vmcnt(0)+barrier.
// MODE 0: bf16 C = acc*scale ; MODE 1: fp8 C = acc*scale
template <int MODE>
__global__ __launch_bounds__(512, 2)
void gemmf8(const unsigned char* A, const unsigned char* Bw, void* __restrict__ Cout,
            int lda, int ldb, int ldc, int K, float scale,
            long sA, long sB, long sC, int zmod) {
    __shared__ __attribute__((aligned(16))) char lds[65536];

    const int gx = gridDim.x;
    const int nblk = gx * gridDim.y;
    const int bid = blockIdx.y * gx + blockIdx.x;
    const int cpx = nblk >> 3;
    const int sbid = (nblk & 7) ? bid : (bid & 7) * cpx + (bid >> 3);
    const int bx = sbid % gx, by = sbid / gx;

    const int z = blockIdx.z;
    const int mat = z % zmod, ks = z / zmod;
    const unsigned char* Ab = A + (long)mat * sA + (long)ks * K;
    const unsigned char* Bb = Bw + (long)mat * sB + (long)ks * K;

    const int t = threadIdx.x;
    const int lane = t & 63;
    const int w = t >> 6;
    const int wm = w >> 2;      // 0..1
    const int wn = w & 3;       // 0..3
    const int l15 = lane & 15;
    const int l4 = lane >> 4;

    const int row0 = by * 256;
    const int col0 = bx * 256;

    // staging: thread t covers unit pos t*16: row r = t>>1, stored-half t&1,
    // global-half u = ((t&1) + (r>>2)) & 1 = ((t&1) + (t>>3)) & 1
    const int r_st = t >> 1;
    const int u_g = ((t & 1) + (t >> 3)) & 1;
    const unsigned char* aSrc = Ab + (long)(row0 + r_st) * lda + u_g * 16;
    const unsigned char* bSrc = Bb + (long)(col0 + r_st) * ldb + u_g * 16;
    const int ld16 = t * 16;

    auto STAGE = [&](int slot, long koff) {
        char* base = lds + slot * 32768;
        gload_lds16(aSrc + koff,      base + ld16);            // A-k0
        gload_lds16(aSrc + koff + 32, base + 8192 + ld16);     // A-k1
        gload_lds16(bSrc + koff,      base + 16384 + ld16);    // B-k0
        gload_lds16(bSrc + koff + 32, base + 24576 + ld16);    // B-k1
    };

    floatx4 acc[8][4] = {};
    const int nk = K / 64;

    STAGE(0, 0);
    VMC(0);
    GBAR();

    for (int s = 0; s < nk; ++s) {
        const char* sb = lds + (s & 1) * 32768;
        const long pko = (long)((s + 1 < nk) ? s + 1 : nk - 1) * 64;
        STAGE((s + 1) & 1, pko);

        auto RD = [&](const char* unit, int r) {
            int addr = r * 32 + ((((l4 >> 1) + (r >> 2)) & 1) << 4) + ((l4 & 1) << 3);
            return *(const long*)(unit + addr);
        };

        long a[8], b[4];
        // kk = 0
#pragma unroll
        for (int n = 0; n < 4; ++n) b[n] = RD(sb + 16384, wn * 64 + n * 16 + l15);
#pragma unroll
        for (int m = 0; m < 8; ++m) a[m] = RD(sb, wm * 128 + m * 16 + l15);
        __builtin_amdgcn_s_setprio(1);
#pragma unroll
        for (int m = 0; m < 8; ++m)
#pragma unroll
            for (int n = 0; n < 4; ++n) acc[m][n] = MFMA8(a[m], b[n], acc[m][n]);
        __builtin_amdgcn_s_setprio(0);
        // kk = 1
#pragma unroll
        for (int n = 0; n < 4; ++n) b[n] = RD(sb + 24576, wn * 64 + n * 16 + l15);
#pragma unroll
        for (int m = 0; m < 8; ++m) a[m] = RD(sb + 8192, wm * 128 + m * 16 + l15);
        __builtin_amdgcn_s_setprio(1);
#pragma unroll
        for (int m = 0; m < 8; ++m)
#pragma unroll
            for (int n = 0; n < 4; ++n) acc[m][n] = MFMA8(a[m], b[n], acc[m][n]);
        __builtin_amdgcn_s_setprio(0);

        VMC(0);
        GBAR();
    }

    const int rq = l4 * 4;
    if constexpr (MODE == 0) {
        bf16* C = ((bf16*)Cout) + (long)z * sC;
#pragma unroll
        for (int m = 0; m < 8; ++m)
#pragma unroll
            for (int i = 0; i < 4; ++i) {
                long gr = row0 + wm * 128 + m * 16 + rq + i;
#pragma unroll
                for (int n = 0; n < 4; ++n) {
                    int gc = col0 + wn * 64 + n * 16 + l15;
                    C[gr * ldc + gc] = (bf16)(acc[m][n][i] * scale);
                }
            }
    } else {
        unsigned char* C = ((unsigned char*)Cout) + (long)z * sC;
#pragma unroll
        for (int m = 0; m < 8; ++m)
#pragma unroll
            for (int i = 0; i < 4; ++i) {
                long gr = row0 + wm * 128 + m * 16 + rq + i;
#pragma unroll
                for (int n = 0; n < 4; ++n) {
                    int gc = col0 + wn * 64 + n * 16 + l15;
                    C[gr * ldc + gc] = to_fp8(acc[m][n][i] * scale);
                }
            }
    }
}

// ---------------- reduce Gt/Wc fp32 partials -> wgc fp8 (x64 scale) ----------------
__global__ void reduce_wgc(const float* __restrict__ p, unsigned char* __restrict__ out) {
    int i = blockIdx.x * blockDim.x + threadIdx.x;
    int e = i * 4;
    int mat = e >> 20;
    int local = e & (WW - 1);
    float4 s = *(const float4*)(p + (long)mat * WW + local);
#pragma unroll
    for (int ksp = 1; ksp < 4; ++ksp) {
        float4 a = *(const float4*)(p + (long)(ksp * 2 + mat) * WW + local);
        s.x += a.x; s.y += a.y; s.z += a.z; s.w += a.w;
    }
    unsigned int pk = to_fp8x2(s.x * 64.f, s.y * 64.f) | (to_fp8x2(s.z * 64.f, s.w * 64.f) << 16);
    *(unsigned int*)&out[e] = pk;
}

// ---------------- row softmax: bf16 scores -> fp8 probs x256 ----------------
__global__ void softmax_rows(const bf16* __restrict__ S, unsigned char* __restrict__ P,
                             const int* __restrict__ mask) {
    const int b = blockIdx.y;
    const int row = blockIdx.x;
    const bf16* srow = S + ((long)b * SEQ + row) * SEQ;
    unsigned char* prow = P + ((long)b * SEQ + row) * SEQ;
    const int* mrow = mask + b * SEQ;
    const int t = threadIdx.x;

    bf16x8 sv = *(const bf16x8*)&srow[t * 8];
    int4 m0 = ((const int4*)mrow)[t * 2];
    int4 m1 = ((const int4*)mrow)[t * 2 + 1];
    int mk[8] = {m0.x, m0.y, m0.z, m0.w, m1.x, m1.y, m1.z, m1.w};

    float v[8];
    float mx = -1e30f;
#pragma unroll
    for (int j = 0; j < 8; ++j) {
        float s = (float)sv[j];
        if (mk[j] == 0) s = -1e9f;
        v[j] = s;
        mx = fmaxf(mx, s);
    }
    __shared__ float redm[4], reds[4];
#pragma unroll
    for (int off = 32; off > 0; off >>= 1) mx = fmaxf(mx, __shfl_down(mx, off));
    if ((t & 63) == 0) redm[t >> 6] = mx;
    __syncthreads();
    mx = fmaxf(fmaxf(redm[0], redm[1]), fmaxf(redm[2], redm[3]));

    float sum = 0.f;
#pragma unroll
    for (int j = 0; j < 8; ++j) {
        v[j] = __expf(v[j] - mx);
        sum += v[j];
    }
#pragma unroll
    for (int off = 32; off > 0; off >>= 1) sum += __shfl_down(sum, off);
    if ((t & 63) == 0) reds[t >> 6] = sum;
    __syncthreads();
    sum = reds[0] + reds[1] + reds[2] + reds[3];
    float inv = 256.0f / sum;

    unsigned int lo = to_fp8x2(v[0] * inv, v[1] * inv) | (to_fp8x2(v[2] * inv, v[3] * inv) << 16);
    unsigned int hi = to_fp8x2(v[4] * inv, v[5] * inv) | (to_fp8x2(v[6] * inv, v[7] * inv) << 16);
    *(uint2*)&prow[t * 8] = make_uint2(lo, hi);
}

// ---------------- transpose VWc fp8 (yv cols 1024..2047) -> vt (1024 x SEQ per batch) ----
__global__ void transpose_v8(const unsigned char* __restrict__ yv, unsigned char* __restrict__ out) {
    __shared__ unsigned char tile[64][68];
    const int z = blockIdx.z;
    const unsigned char* ib = yv + (long)z * SEQ * 2048 + 1024;
    unsigned char* ob = out + (long)z * (long)HIDDEN * SEQ;
    const int d0 = blockIdx.x * 64;
    const int s0 = blockIdx.y * 64;
    const int t = threadIdx.x;
    const int r = t >> 4;
    const int c = (t & 15) * 4;
#pragma unroll
    for (int i = 0; i < 4; ++i) {
        uchar4 v = *(const uchar4*)&ib[(long)(s0 + r + i * 16) * 2048 + d0 + c];
        *(uchar4*)&tile[r + i * 16][c] = v;
    }
    __syncthreads();
#pragma unroll
    for (int i = 0; i < 4; ++i) {
        const int dr = r + i * 16;
        uchar4 o;
        o.x = tile[c + 0][dr]; o.y = tile[c + 1][dr];
        o.z = tile[c + 2][dr]; o.w = tile[c + 3][dr];
        *(uchar4*)&ob[(long)(d0 + dr) * SEQ + s0 + c] = o;
    }
}

// ---------------- LayerNorm fused with PV split-K reduce + bias + residual ----------------
__global__ void layernorm_out(const bf16* __restrict__ pp, const float* __restrict__ x,
                              const float* __restrict__ bo, const float* __restrict__ gamma,
                              const float* __restrict__ beta, float* __restrict__ out) {
    const long row = blockIdx.x;
    const int b = (int)(row >> 11);
    const int s = (int)(row & 2047);
    const bf16* r0 = pp + ((long)b * SEQ + s) * HIDDEN;
    const bf16* r1 = r0 + 4L * SEQ * HIDDEN;
    const int t = threadIdx.x;

    bf16x4 a0 = ((const bf16x4*)r0)[t];
    bf16x4 a1 = ((const bf16x4*)r1)[t];
    float4 xv = ((const float4*)(x + row * HIDDEN))[t];
    float4 bv = ((const float4*)bo)[t];
    float4 v;
    v.x = (float)a0[0] + (float)a1[0] + bv.x + xv.x;
    v.y = (float)a0[1] + (float)a1[1] + bv.y + xv.y;
    v.z = (float)a0[2] + (float)a1[2] + bv.z + xv.z;
    v.w = (float)a0[3] + (float)a1[3] + bv.w + xv.w;

    float ssum = v.x + v.y + v.z + v.w;
    float sq = v.x * v.x + v.y * v.y + v.z * v.z + v.w * v.w;
    __shared__ float rs[4], rq[4];
#pragma unroll
    for (int off = 32; off > 0; off >>= 1) {
        ssum += __shfl_down(ssum, off);
        sq += __shfl_down(sq, off);
    }
    if ((t & 63) == 0) { rs[t >> 6] = ssum; rq[t >> 6] = sq; }
    __syncthreads();
    ssum = rs[0] + rs[1] + rs[2] + rs[3];
    sq = rq[0] + rq[1] + rq[2] + rq[3];
    float mu = ssum * (1.0f / HIDDEN);
    float var = sq * (1.0f / HIDDEN) - mu * mu;
    float rinv = rsqrtf(var + LN_EPS);
    float4 g = ((const float4*)gamma)[t];
    float4 bt = ((const float4*)beta)[t];
    float4 o;
    o.x = (v.x - mu) * rinv * g.x + bt.x;
    o.y = (v.y - mu) * rinv * g.y + bt.y;
    o.z = (v.z - mu) * rinv * g.z + bt.z;
    o.w = (v.w - mu) * rinv * g.w + bt.w;
    ((float4*)(out + row * HIDDEN))[t] = o;
}

// ---------------- launch ----------------
extern "C" void kernel_launch(void* const* d_in, const int* in_sizes, int n_in,
                              void* d_out, int out_size, void* d_ws, size_t ws_size,
                              hipStream_t stream) {
    const float* x     = (const float*)d_in[0];
    const int*   mask  = (const int*)d_in[1];
    const float* Wq    = (const float*)d_in[2];
    const float* Wk    = (const float*)d_in[3];
    const float* Wv    = (const float*)d_in[4];
    const float* Wo    = (const float*)d_in[5];
    const float* bo    = (const float*)d_in[6];
    const float* gamma = (const float*)d_in[7];
    const float* beta  = (const float*)d_in[8];
    float* out = (float*)d_out;

    char* ws = (char*)d_ws;
    const long MB = 1024L * 1024L;
    unsigned char* xb8  = (unsigned char*)(ws + 0 * MB);   // 8 MB (8192x1024 fp8)
    unsigned char* yv8  = (unsigned char*)(ws + 8 * MB);   // 16 MB (8192x2048 fp8) [y | VWc]
    unsigned char* vt8  = (unsigned char*)(ws + 24 * MB);  // 8 MB (per batch 1024x2048 fp8)
    unsigned char* wgc8 = (unsigned char*)(ws + 32 * MB);  // 2 MB (2048x1024 fp8, x64)
    bf16* wkT = (bf16*)(ws + 34 * MB);                     // 2 MB
    bf16* wo  = (bf16*)(ws + 36 * MB);                     // 2 MB
    bf16* wqT = (bf16*)(ws + 38 * MB);                     // 2 MB
    bf16* wvT = (bf16*)(ws + 40 * MB);                     // 2 MB
    bf16* S   = (bf16*)(ws + 42 * MB);                     // 32 MB bf16 scores
    float* wgcp = (float*)(ws + 42 * MB);                  // 32 MB fp32 partials (dead before S)
    bf16* pp  = (bf16*)(ws + 42 * MB);                     // 32 MB PV partials (over S, after softmax)
    unsigned char* P8 = (unsigned char*)(ws + 74 * MB);    // 16 MB fp8 probs x256

    const int BS = BATCH * SEQ;  // 8192
    dim3 blk256(256), blk512(512);

    // input + weight prep
    cvt_f32_fp8<<<dim3(BS * HIDDEN / 8 / 256), blk256, 0, stream>>>(x, xb8, BS * HIDDEN / 8);
    cvt_f32_bf16<<<dim3(WW / 4 / 256), blk256, 0, stream>>>(Wo, wo, WW / 4);
    transpose_w3<<<dim3(16, 16, 3), blk256, 0, stream>>>(Wq, Wk, Wv, wqT, wkT, wvT);

    // Gt/Wc split-K=4 (bf16): z = ks*2 + mat, K_sub=256, fp32 partials. grid (4,4,8)
    gemm8p<4><<<dim3(1024 / 256, 1024 / 256, 8), blk512, 0, stream>>>(
        wkT, wqT, wgcp, HIDDEN, HIDDEN, HIDDEN, 256, 1.0f,
        (long)WW, (long)WW, (long)WW, 2);
    reduce_wgc<<<dim3(2 * WW / 4 / 256), blk256, 0, stream>>>(wgcp, wgc8);

    // fused projection (fp8): yv8 = xb8 * wgc8^T / 64. grid 8x32 = 256
    gemmf8<1><<<dim3(2048 / 256, BS / 256, 1), blk512, 0, stream>>>(
        xb8, wgc8, yv8, HIDDEN, HIDDEN, 2048, HIDDEN, 1.0f / 64.0f, 0, 0, 0, 1);

    // VWc -> vt per batch (fp8)
    transpose_v8<<<dim3(HIDDEN / 64, SEQ / 64, BATCH), blk256, 0, stream>>>(yv8, vt8);

    // scores (fp8 in, bf16 out): per batch y * x^T * SCALE. grid 8x8x4 = 256
    gemmf8<0><<<dim3(SEQ / 256, SEQ / 256, BATCH), blk512, 0, stream>>>(
        yv8, xb8, S, 2048, HIDDEN, SEQ, HIDDEN, ATT_SCALE,
        (long)SEQ * 2048, (long)SEQ * HIDDEN, (long)SEQ * SEQ, 4);

    // softmax -> fp8 probs x256
    softmax_rows<<<dim3(SEQ, BATCH), blk256, 0, stream>>>(S, P8, mask);

    // PV split-K=2 (fp8): z = ks*4 + b, K_sub=1024, bf16 partials x(1/256). grid (4,8,8)
    gemmf8<0><<<dim3(HIDDEN / 256, SEQ / 256, 8), blk512, 0, stream>>>(
        P8, vt8, pp, SEQ, SEQ, HIDDEN, 1024, 1.0f / 256.0f,
        (long)SEQ * SEQ, (long)HIDDEN * SEQ, (long)SEQ * HIDDEN, 4);

    // LN fused with partial-reduce + bias + residual
    layernorm_out<<<dim3(BS), blk256, 0, stream>>>(pp, x, bo, gamma, beta, out);
}